// Round 9
// baseline (609.679 us; speedup 1.0000x reference)
//
#include <hip/hip_runtime.h>
#include <hip/hip_bf16.h>
#include <math.h>

// Problem constants (from reference setup_inputs)
#define NN   100000
#define ICH  6
#define OCH  32
#define NBK  782      // ceil(2*NN / 256) buckets of 256 bins
#define PBLK 256      // partition blocks / K1 grid
#define CAP  8192     // pass-B LDS staging capacity (mean bucket = 4096)
#define K2B  768      // K2 grid (3 blocks/CU avg, 4/CU capacity -> slack)
#define NT   6250     // node tiles of 16 (= NN/16)

// Dual-dtype load: harness may hand bf16-converted or raw fp32 inputs.
__device__ __forceinline__ float ldf(const void* p, long i, int f32) {
    return f32 ? ((const float*)p)[i]
               : __bfloat162float(((const __hip_bfloat16*)p)[i]);
}
__device__ __forceinline__ float lo16f(unsigned u) { return __uint_as_float(u << 16); }
__device__ __forceinline__ float hi16f(unsigned u) { return __uint_as_float(u & 0xFFFF0000u); }

// Grid barrier: monotone counter, release on arrive, acquire on spin.
// All blocks are co-resident by construction (occupancy slack documented at
// each launch site), so spinning is deadlock-free.
__device__ __forceinline__ void gridbar(int* bar, int target) {
    __syncthreads();
    if (threadIdx.x == 0) {
        __threadfence();
        __hip_atomic_fetch_add(bar, 1, __ATOMIC_ACQ_REL, __HIP_MEMORY_SCOPE_AGENT);
        while (__hip_atomic_load(bar, __ATOMIC_ACQUIRE, __HIP_MEMORY_SCOPE_AGENT) < target)
            __builtin_amdgcn_s_sleep(2);
    }
    __syncthreads();
}

// ---------------------------------------------------------------------------
// K1: dtype detect + xpack + full CSR build (4 phases, 3 grid barriers).
// Grid 256 x 1024 = 16 waves/CU occupied; capacity far higher -> all resident.
__global__ __launch_bounds__(1024, 8) void csr_r9(
        const int* __restrict__ edge_tp, const int* __restrict__ edge_int,
        int Etp, int Eint,
        const void* __restrict__ x, unsigned* __restrict__ xw,
        int* __restrict__ mat, int* __restrict__ bsum,
        int* __restrict__ off, int* __restrict__ csr,
        unsigned* __restrict__ part, int* __restrict__ flagp, int* __restrict__ bar) {
    __shared__ union {
        struct { int lh[NBK]; int weird; } a1;
        struct { int sc[1024]; } sca;
        struct { int cur[NBK]; int bsx[256]; } a2;
        struct { unsigned lp[CAP]; int ssc[256]; int scur[256]; int bsx[256]; } b;
    } U;
    const int t = threadIdx.x, blk = blockIdx.x;
    const int E = Etp + Eint;
    const int* src_tp  = edge_tp;
    const int* dst_tp  = edge_tp + Etp;
    const int* src_int = edge_int;
    const int* dst_int = edge_int + Eint;
    const int CH = (E + PBLK - 1) / PBLK;

    // ---- phase A1: bucket histogram (+ dtype detect on block 0) ----
    if (t == 0) U.a1.weird = 0;
    for (int b = t; b < NBK; b += 1024) U.a1.lh[b] = 0;
    __syncthreads();
    if (blk == 0) {
        const __hip_bfloat16* p = (const __hip_bfloat16*)x;
        int w = 0;
        for (int i = t; i < 4096; i += 1024) {
            float v = fabsf(__bfloat162float(p[i]));
            if (!(v <= 1000.0f) || (v > 0.0f && v < 1e-4f)) w++;
        }
        if (w) atomicAdd(&U.a1.weird, w);
    }
    {
        int lo = blk * CH, hi = min(E, lo + CH);
        for (int e = lo + t; e < hi; e += 1024) {
            int bin = (e < Etp) ? dst_tp[e] : NN + dst_int[e - Etp];
            atomicAdd(&U.a1.lh[bin >> 8], 1);
        }
    }
    __syncthreads();
    if (blk == 0 && t == 0) *flagp = (U.a1.weird > 500) ? 1 : 0;
    for (int b = t; b < NBK; b += 1024) mat[b * PBLK + blk] = U.a1.lh[b];
    gridbar(bar, PBLK);

    // ---- phase scan: per-block chunk scan of mat (782 elems) + xpack ----
    {
        int f32 = *flagp;
        for (int w = blk * 1024 + t; w < NN * 4; w += PBLK * 1024) {
            int n = w >> 2, j = w & 3;
            int c0 = 2 * j, c1 = 2 * j + 1;
            __hip_bfloat16 v0 = (c0 < ICH) ? __float2bfloat16(ldf(x, (long)n * ICH + c0, f32))
                                           : __float2bfloat16(0.0f);
            __hip_bfloat16 v1 = (c1 < ICH) ? __float2bfloat16(ldf(x, (long)n * ICH + c1, f32))
                                           : __float2bfloat16(0.0f);
            xw[w] = (unsigned)__bfloat16_as_ushort(v0) |
                    ((unsigned)__bfloat16_as_ushort(v1) << 16);
        }
        const int n0 = blk * 782;                 // 782*256 == NBK*PBLK exactly
        int v = (t < 782) ? mat[n0 + t] : 0;
        U.sca.sc[t] = v;
        __syncthreads();
        for (int d = 1; d < 1024; d <<= 1) {
            int val = (t >= d) ? U.sca.sc[t - d] : 0;
            __syncthreads();
            U.sca.sc[t] += val;
            __syncthreads();
        }
        if (t < 782) mat[n0 + t] = U.sca.sc[t] - v;   // chunk-exclusive
        if (t == 1023) bsum[blk] = U.sca.sc[1023];
    }
    gridbar(bar, 2 * PBLK);

    // ---- phase A2: partition edges into bucket-contiguous part[] ----
    {
        int v = (t < 256) ? bsum[t] : 0;
        U.a2.bsx[t < 256 ? t : 0] = 0;   // placate; real write below
        __syncthreads();
        if (t < 256) U.a2.bsx[t] = v;
        __syncthreads();
        for (int d = 1; d < 256; d <<= 1) {
            int val = (t >= d && t < 256) ? U.a2.bsx[t - d] : 0;
            __syncthreads();
            if (t < 256) U.a2.bsx[t] += val;
            __syncthreads();
        }
        if (t < 256) U.a2.bsx[t] -= v;    // exclusive
        __syncthreads();
        for (int b = t; b < NBK; b += 1024) {
            int idx = b * PBLK + blk;
            U.a2.cur[b] = mat[idx] + U.a2.bsx[idx / 782];
        }
        __syncthreads();
        int lo = blk * CH, hi = min(E, lo + CH);
        for (int e = lo + t; e < hi; e += 1024) {
            int bin, src;
            if (e < Etp) { bin = dst_tp[e]; src = src_tp[e]; }
            else         { bin = NN + dst_int[e - Etp]; src = src_int[e - Etp]; }
            int pos = atomicAdd(&U.a2.cur[bin >> 8], 1);
            part[pos] = ((unsigned)(bin & 255) << 24) | (unsigned)src;
        }
    }
    gridbar(bar, 3 * PBLK);

    // ---- phase B: per-bucket bin sort -> off/csr ----
    {
        int v = (t < 256) ? bsum[t] : 0;
        __syncthreads();
        if (t < 256) U.b.bsx[t] = v;
        __syncthreads();
        for (int d = 1; d < 256; d <<= 1) {
            int val = (t >= d && t < 256) ? U.b.bsx[t - d] : 0;
            __syncthreads();
            if (t < 256) U.b.bsx[t] += val;
            __syncthreads();
        }
        if (t < 256) U.b.bsx[t] -= v;
        __syncthreads();
        for (int kb = blk; kb < NBK; kb += PBLK) {
            int s0 = mat[kb * PBLK] + U.b.bsx[(kb * PBLK) / 782];
            int s1 = (kb + 1 < NBK) ? mat[(kb + 1) * PBLK] + U.b.bsx[((kb + 1) * PBLK) / 782] : E;
            int cnt = s1 - s0;
            if (t < 256) U.b.scur[t] = 0;
            __syncthreads();
            for (int i = t; i < cnt; i += 1024) {
                unsigned v2 = part[s0 + i];
                if (i < CAP) U.b.lp[i] = v2;
                atomicAdd(&U.b.scur[v2 >> 24], 1);
            }
            __syncthreads();
            int own = (t < 256) ? U.b.scur[t] : 0;
            if (t < 256) U.b.ssc[t] = own;
            __syncthreads();
            for (int d = 1; d < 256; d <<= 1) {
                int val = (t >= d && t < 256) ? U.b.ssc[t - d] : 0;
                __syncthreads();
                if (t < 256) U.b.ssc[t] += val;
                __syncthreads();
            }
            if (t < 256) {
                int excl = U.b.ssc[t] - own;
                U.b.scur[t] = excl;
                int gbin = kb * 256 + t;
                if (gbin <= 2 * NN) off[gbin] = s0 + excl;
            }
            __syncthreads();
            for (int i = t; i < cnt; i += 1024) {
                unsigned v2 = (i < CAP) ? U.b.lp[i] : part[s0 + i];
                int pos = atomicAdd(&U.b.scur[v2 >> 24], 1);
                csr[s0 + pos] = (int)(v2 & 0xFFFFFFu);
            }
            __syncthreads();     // scur/lp reuse safety for next kb
        }
    }
}

// ---------------------------------------------------------------------------
// K2: node1 (block-1 transform) + grid barrier + final (block-2 + decoder).
// Grid 768 x 512: 24 waves/CU avg; capacity 4 blocks/CU (LDS 24.2 KB,
// VGPR capped by launch_bounds) -> all resident, barrier-safe.
__global__ __launch_bounds__(512, 8) void node_final_r9(
        const void* __restrict__ x, const unsigned* __restrict__ xw,
        const int* __restrict__ csr, const int* __restrict__ off,
        const void* Ws1, const void* b1, const void* Wt1, const void* Wi1, const void* Wr1,
        const void* Ws2, const void* b2v, const void* Wt2, const void* Wi2,
        const void* Wd1, const void* bd1, const void* Wd2, const void* bd2,
        __hip_bfloat16* __restrict__ h1b, float* __restrict__ invc_a,
        void* __restrict__ out, const int* __restrict__ flag, int* __restrict__ bar) {
    __shared__ union {
        struct {
            float sWs[ICH * OCH], sWt[ICH * OCH], sWi[ICH * OCH], sb1[OCH];
            float sag[16][2][8];
        } n1;
        struct {
            float sWcatT[32][100]; float sWdT[32][36];
            float sb2[OCH], sbd1[OCH], swd2[OCH];
            float sv[16][100];
        } fi;
    } S;
    const int t = threadIdx.x, blk = blockIdx.x;
    const int f32 = *flag;
    const int g = t >> 5, c = t & 31;
    const unsigned* h1u = (const unsigned*)h1b;

    // ================= phase 1: node1 =================
    if (t < ICH * OCH) {
        S.n1.sWs[t] = ldf(Ws1, t, f32) + ldf(Wr1, t, f32);   // fold residual proj
        S.n1.sWt[t] = ldf(Wt1, t, f32);
        S.n1.sWi[t] = ldf(Wi1, t, f32);
    }
    if (t < OCH) S.n1.sb1[t] = ldf(b1, t, f32);
    __syncthreads();

    {
        int s = c >> 2, j = c & 3;
        for (int tile = blk; tile < NT; tile += K2B) {
            int node = tile * 16 + g;           // NT*16 == NN exactly
#pragma unroll
            for (int set = 0; set < 2; ++set) {
                int s0 = off[set * NN + node], s1 = off[set * NN + node + 1];
                float vx = 0.0f, vy = 0.0f;
                for (int base = s0; base < s1; base += 32) {
                    int m = s1 - base; if (m > 32) m = 32;
                    int idx = csr[base + (c < m ? c : m - 1)];
                    for (int b2 = 0; b2 < m; b2 += 16) {   // 16-edge steps: less waste
                        unsigned u[2];
#pragma unroll
                        for (int q = 0; q < 2; ++q) {
                            int e = b2 + q * 8 + s;
                            int sj = __shfl(idx, e & 31, 32);
                            u[q] = xw[(unsigned)sj * 4u + j];
                        }
#pragma unroll
                        for (int q = 0; q < 2; ++q) {
                            unsigned um = (b2 + q * 8 + s < m) ? u[q] : 0u;
                            vx += lo16f(um); vy += hi16f(um);
                        }
                    }
                }
                vx += __shfl_down(vx, 16, 32);  vy += __shfl_down(vy, 16, 32);
                vx += __shfl_down(vx, 8, 32);   vy += __shfl_down(vy, 8, 32);
                vx += __shfl_down(vx, 4, 32);   vy += __shfl_down(vy, 4, 32);
                if (c < 4) { S.n1.sag[g][set][2 * j] = vx; S.n1.sag[g][set][2 * j + 1] = vy; }
                // same-wave producer/consumer
            }
            int degi = off[NN + node + 1] - off[NN + node];
            float invc = 1.0f / fmaxf((float)degi, 1.0f);
            float acc = S.n1.sb1[c];
#pragma unroll
            for (int k = 0; k < ICH; ++k) {
                float xv = ldf(x, (long)node * ICH + k, f32);
                acc += xv * S.n1.sWs[k * OCH + c]
                     + S.n1.sag[g][0][k] * S.n1.sWt[k * OCH + c]
                     + (S.n1.sag[g][1][k] * invc) * S.n1.sWi[k * OCH + c];
            }
            h1b[(long)node * OCH + c] = __float2bfloat16(fmaxf(acc, 0.0f));
            if (c == 0) invc_a[node] = invc;
        }
    }

    gridbar(bar, K2B);

    // ================= phase 2: final =================
    for (int i = t; i < 96 * 32; i += 512) {
        int k = i >> 5, cc = i & 31;
        float w;
        if (k < 32)      w = ldf(Ws2, k * 32 + cc, f32) + ((k == cc) ? 1.0f : 0.0f);
        else if (k < 64) w = ldf(Wt2, (k - 32) * 32 + cc, f32);
        else             w = ldf(Wi2, (k - 64) * 32 + cc, f32);
        S.fi.sWcatT[cc][k] = w;
    }
    for (int i = t; i < 32 * 32; i += 512) {
        int k = i >> 5, cc = i & 31;
        S.fi.sWdT[cc][k] = ldf(Wd1, k * 32 + cc, f32);
    }
    if (t < OCH) {
        S.fi.sb2[t] = ldf(b2v, t, f32); S.fi.sbd1[t] = ldf(bd1, t, f32);
        S.fi.swd2[t] = ldf(Wd2, t, f32);
    }
    __syncthreads();

    {
        int half = c >> 4, l = c & 15;
        for (int tile = blk; tile < NT; tile += K2B) {
            int node = tile * 16 + g;
            {
                unsigned u = h1u[(unsigned)node * 16u + l];
                if (half == 0)
                    *(float2*)&S.fi.sv[g][2 * l] = make_float2(lo16f(u), hi16f(u));
            }
            float ic = invc_a[node];
#pragma unroll
            for (int set = 0; set < 2; ++set) {
                int s0 = off[set * NN + node], s1 = off[set * NN + node + 1];
                float vx = 0.0f, vy = 0.0f;
                for (int base = s0; base < s1; base += 32) {
                    int m = s1 - base; if (m > 32) m = 32;
                    int idx = csr[base + (c < m ? c : m - 1)];
                    for (int b = 0; b < m; b += 8) {       // 8-edge steps: less waste
                        unsigned uu[4];
#pragma unroll
                        for (int q = 0; q < 4; ++q) {
                            int e = b + 2 * q + half;
                            int sj = __shfl(idx, e & 31, 32);
                            uu[q] = h1u[(unsigned)sj * 16u + l];
                        }
#pragma unroll
                        for (int q = 0; q < 4; ++q) {
                            unsigned um = (b + 2 * q + half < m) ? uu[q] : 0u;
                            vx += lo16f(um); vy += hi16f(um);
                        }
                    }
                }
                vx += __shfl_down(vx, 16, 32);
                vy += __shfl_down(vy, 16, 32);
                if (half == 0) {
                    float sc = (set == 1) ? ic : 1.0f;
                    *(float2*)&S.fi.sv[g][32 + set * 32 + 2 * l] = make_float2(vx * sc, vy * sc);
                }
            }
            // same-wave LDS producer/consumer: program order suffices

            float acc = S.fi.sb2[c];
#pragma unroll
            for (int k4 = 0; k4 < 24; ++k4) {
                float4 w = *(const float4*)&S.fi.sWcatT[c][4 * k4];
                float4 v = *(const float4*)&S.fi.sv[g][4 * k4];
                acc += w.x * v.x + w.y * v.y + w.z * v.z + w.w * v.w;
            }
            float h2 = fmaxf(acc, 0.0f);
            S.fi.sv[g][c] = h2;     // same-wave lockstep => safe overwrite

            float acc2 = S.fi.sbd1[c];
#pragma unroll
            for (int k4 = 0; k4 < 8; ++k4) {
                float4 w = *(const float4*)&S.fi.sWdT[c][4 * k4];
                float4 v = *(const float4*)&S.fi.sv[g][4 * k4];
                acc2 += w.x * v.x + w.y * v.y + w.z * v.z + w.w * v.w;
            }
            float h3 = fmaxf(acc2, 0.0f);

            float p = h3 * S.fi.swd2[c];
#pragma unroll
            for (int offs = 16; offs; offs >>= 1) p += __shfl_down(p, offs, 32);
            if (c == 0) {
                float z = p + ldf(bd2, 0, f32);
                float sgm = 1.0f / (1.0f + expf(-z));
                if (f32) ((float*)out)[node] = sgm;
                else     ((__hip_bfloat16*)out)[node] = __float2bfloat16(sgm);
            }
        }
    }
}

// ---------------------------------------------------------------------------
extern "C" void kernel_launch(void* const* d_in, const int* in_sizes, int n_in,
                              void* d_out, int out_size, void* d_ws, size_t ws_size,
                              hipStream_t stream) {
    const void* x      = d_in[0];
    const int* edge_tp = (const int*)d_in[1];
    const int* edge_int= (const int*)d_in[2];
    const void* Ws1 = d_in[3], *b1 = d_in[4], *Wt1 = d_in[5], *Wi1 = d_in[6], *Wr1 = d_in[7];
    const void* Ws2 = d_in[8], *b2 = d_in[9];
    const void* Wt2 = d_in[10], *Wi2 = d_in[11];
    const void* Wd1 = d_in[12], *bd1 = d_in[13], *Wd2 = d_in[14], *bd2 = d_in[15];

    const int E_tp  = in_sizes[1] / 2;
    const int E_int = in_sizes[2] / 2;
    const int E     = E_tp + E_int;

    // Workspace (4B units), ~29 MB (same proven-safe footprint as r8):
    // [bar/flag:64][mat: NBK*PBLK][bsum:256][off: 2N+2][xw: 4N][csr: E][union: E]
    //   union holds part during K1, then h1b(16N)+invc(N) in K2.
    int*      bar  = (int*)d_ws;          // bar[0]=K1 counter, bar[1]=K2 counter
    int*      flag = bar + 8;
    int*      mat  = bar + 64;
    int*      bsum = mat + NBK * PBLK;
    int*      off  = bsum + 256;
    unsigned* xw   = (unsigned*)(off + 2 * NN + 2);
    int*      csr  = (int*)(xw + (size_t)4 * NN);
    int*      un   = csr + E;
    unsigned* part = (unsigned*)un;
    __hip_bfloat16* h1b = (__hip_bfloat16*)un;
    float*    invc = (float*)(un + (size_t)16 * NN);

    hipMemsetAsync(bar, 0, 64 * sizeof(int), stream);   // barrier counters + flag

    csr_r9<<<PBLK, 1024, 0, stream>>>(edge_tp, edge_int, E_tp, E_int,
                                      x, xw, mat, bsum, off, csr, part, flag, bar);

    node_final_r9<<<K2B, 512, 0, stream>>>(x, xw, csr, off,
                                           Ws1, b1, Wt1, Wi1, Wr1,
                                           Ws2, b2, Wt2, Wi2,
                                           Wd1, bd1, Wd2, bd2,
                                           h1b, invc, d_out, flag, bar + 1);
}

// Round 10
// 264.410 us; speedup vs baseline: 2.3058x; 2.3058x over previous
//
#include <hip/hip_runtime.h>
#include <hip/hip_bf16.h>
#include <math.h>

// Problem constants (from reference setup_inputs)
#define NN   100000
#define ICH  6
#define OCH  32
#define NBK  782      // ceil(2*NN / 256) buckets of 256 bins
#define PBLK 256      // partition blocks (pass A)
#define CAP  8192     // pass-B LDS staging capacity (mean bucket = 4096)
#define GN   16       // final: nodes per block (512 threads)

// Dual-dtype load: harness may hand bf16-converted or raw fp32 inputs.
__device__ __forceinline__ float ldf(const void* p, long i, int f32) {
    return f32 ? ((const float*)p)[i]
               : __bfloat162float(((const __hip_bfloat16*)p)[i]);
}
__device__ __forceinline__ float lo16f(unsigned u) { return __uint_as_float(u << 16); }
__device__ __forceinline__ float hi16f(unsigned u) { return __uint_as_float(u & 0xFFFF0000u); }

// ---------------------------------------------------------------------------
// partA1 + dtype detect (block 0). Per-block bucket histogram, LDS-privatized.
__global__ __launch_bounds__(1024) void partA1_r10(
        const int* __restrict__ dst_tp, const int* __restrict__ dst_int,
        int* __restrict__ mat, int Etp, int E,
        const void* __restrict__ x, int* __restrict__ flagp) {
    __shared__ int lh[NBK];
    __shared__ int weird;
    int t = threadIdx.x;
    if (t == 0) weird = 0;
    for (int b = t; b < NBK; b += 1024) lh[b] = 0;
    __syncthreads();
    if (blockIdx.x == 0 && t < 256) {     // dtype detection (fused)
        const __hip_bfloat16* p = (const __hip_bfloat16*)x;
        int w = 0;
        for (int i = t; i < 4096; i += 256) {
            float v = fabsf(__bfloat162float(p[i]));
            if (!(v <= 1000.0f) || (v > 0.0f && v < 1e-4f)) w++;
        }
        atomicAdd(&weird, w);
    }
    int CH = (E + PBLK - 1) / PBLK;
    int lo = blockIdx.x * CH, hi = min(E, lo + CH);
    for (int e = lo + t; e < hi; e += 1024) {
        int bin = (e < Etp) ? dst_tp[e] : NN + dst_int[e - Etp];
        atomicAdd(&lh[bin >> 8], 1);
    }
    __syncthreads();
    if (blockIdx.x == 0 && t == 0) *flagp = (weird > 500) ? 1 : 0;
    for (int b = t; b < NBK; b += 1024) mat[b * PBLK + blockIdx.x] = lh[b];
}

__global__ __launch_bounds__(256) void scan_block_r10(const int* __restrict__ in,
                                                      int* __restrict__ out,
                                                      int* __restrict__ bsum, int n) {
    __shared__ int sh[256];
    int t = threadIdx.x;
    int base = blockIdx.x * 1024 + t * 4;
    int v[4], s = 0;
#pragma unroll
    for (int i = 0; i < 4; ++i) { v[i] = (base + i < n) ? in[base + i] : 0; s += v[i]; }
    sh[t] = s; __syncthreads();
    for (int d = 1; d < 256; d <<= 1) {
        int val = (t >= d) ? sh[t - d] : 0;
        __syncthreads();
        sh[t] += val;
        __syncthreads();
    }
    int excl = sh[t] - s;
#pragma unroll
    for (int i = 0; i < 4; ++i) { if (base + i < n) out[base + i] = excl; excl += v[i]; }
    if (t == 255) bsum[blockIdx.x] = sh[255];
}

// scan_add with the (tiny) top-level bsum scan re-done per block.
__global__ __launch_bounds__(256) void scan_add_r10(int* __restrict__ off,
                                                    const int* __restrict__ bsum,
                                                    int n, int nb) {
    __shared__ int sh[256], spre[256];
    int t = threadIdx.x;
    int v = (t < nb) ? bsum[t] : 0;
    sh[t] = v; __syncthreads();
    for (int d = 1; d < 256; d <<= 1) {
        int val = (t >= d) ? sh[t - d] : 0;
        __syncthreads();
        sh[t] += val;
        __syncthreads();
    }
    spre[t] = sh[t] - v;
    __syncthreads();
    int i = blockIdx.x * 256 + t;
    if (i < n) off[i] += spre[i >> 10];
}

__global__ __launch_bounds__(1024) void partA2_r10(
        const int* __restrict__ src_tp, const int* __restrict__ dst_tp,
        const int* __restrict__ src_int, const int* __restrict__ dst_int,
        const int* __restrict__ mat, unsigned* __restrict__ part, int Etp, int E) {
    __shared__ int cur[NBK];
    int t = threadIdx.x;
    for (int b = t; b < NBK; b += 1024) cur[b] = mat[b * PBLK + blockIdx.x];
    __syncthreads();
    int CH = (E + PBLK - 1) / PBLK;
    int lo = blockIdx.x * CH, hi = min(E, lo + CH);
    for (int e = lo + t; e < hi; e += 1024) {
        int bin, src;
        if (e < Etp) { bin = dst_tp[e]; src = src_tp[e]; }
        else         { bin = NN + dst_int[e - Etp]; src = src_int[e - Etp]; }
        int pos = atomicAdd(&cur[bin >> 8], 1);
        part[pos] = ((unsigned)(bin & 255) << 24) | (unsigned)src;
    }
}

// passB + xpack fused: block k also packs xw words [k*512, k*512+512).
__global__ __launch_bounds__(256) void passB_r10(
        const unsigned* __restrict__ part, const int* __restrict__ mat,
        int* __restrict__ off, int* __restrict__ csr, int E,
        const void* __restrict__ x, unsigned* __restrict__ xw,
        const int* __restrict__ flag) {
    __shared__ unsigned lp[CAP];
    __shared__ int ssc[256], scur[256];
    int k = blockIdx.x, t = threadIdx.x;
    // ---- xpack slice (independent work; issues early) ----
    int f32 = *flag;
#pragma unroll
    for (int r = 0; r < 2; ++r) {
        int w = k * 512 + r * 256 + t;
        if (w < NN * 4) {
            int n = w >> 2, j = w & 3;
            int c0 = 2 * j, c1 = 2 * j + 1;
            __hip_bfloat16 v0 = (c0 < ICH) ? __float2bfloat16(ldf(x, (long)n * ICH + c0, f32))
                                           : __float2bfloat16(0.0f);
            __hip_bfloat16 v1 = (c1 < ICH) ? __float2bfloat16(ldf(x, (long)n * ICH + c1, f32))
                                           : __float2bfloat16(0.0f);
            xw[w] = (unsigned)__bfloat16_as_ushort(v0) |
                    ((unsigned)__bfloat16_as_ushort(v1) << 16);
        }
    }
    // ---- bucket -> bin sort ----
    int s0 = mat[k * PBLK];
    int s1 = (k + 1 < NBK) ? mat[(k + 1) * PBLK] : E;
    int cnt = s1 - s0;
    scur[t] = 0;
    __syncthreads();
    for (int i = t; i < cnt; i += 256) {
        unsigned v = part[s0 + i];
        if (i < CAP) lp[i] = v;
        atomicAdd(&scur[v >> 24], 1);
    }
    __syncthreads();
    int own = scur[t];
    ssc[t] = own; __syncthreads();
    for (int d = 1; d < 256; d <<= 1) {
        int val = (t >= d) ? ssc[t - d] : 0;
        __syncthreads();
        ssc[t] += val;
        __syncthreads();
    }
    int excl = ssc[t] - own;
    scur[t] = excl;
    int gbin = k * 256 + t;
    if (gbin <= 2 * NN) off[gbin] = s0 + excl;
    __syncthreads();
    for (int i = t; i < cnt; i += 256) {
        unsigned v = (i < CAP) ? lp[i] : part[s0 + i];
        int pos = atomicAdd(&scur[v >> 24], 1);
        csr[s0 + pos] = (int)(v & 0xFFFFFFu);
    }
}

// ---------------------------------------------------------------------------
// Block-1: gather packed 16 B x-rows. 8 edge-slots x 4 dword-lanes per group.
// Both sets' first-window csr indices prefetched up front.
__global__ __launch_bounds__(256, 8) void node1_r10(
        const void* __restrict__ x, const unsigned* __restrict__ xw,
        const int* __restrict__ csr, const int* __restrict__ off,
        const void* Ws1, const void* b1, const void* Wt1, const void* Wi1, const void* Wr1,
        __hip_bfloat16* __restrict__ h1b, float* __restrict__ invc_out,
        const int* __restrict__ flag) {
    __shared__ float sWs[ICH * OCH], sWt[ICH * OCH], sWi[ICH * OCH], sb1[OCH];
    __shared__ float sag[8][2][8];
    int t = threadIdx.x;
    int f32 = *flag;
    if (t < ICH * OCH) {
        sWs[t] = ldf(Ws1, t, f32) + ldf(Wr1, t, f32);   // fold residual proj
        sWt[t] = ldf(Wt1, t, f32);
        sWi[t] = ldf(Wi1, t, f32);
    }
    if (t < OCH) sb1[t] = ldf(b1, t, f32);
    __syncthreads();

    int g = t >> 5, c = t & 31;
    int s = c >> 2, j = c & 3;
    int node = blockIdx.x * 8 + g;

    // front-load both sets' extents + first-window indices
    int sa0 = off[node],      sa1 = off[node + 1];
    int sb0 = off[NN + node], sb1_ = off[NN + node + 1];
    int ma0 = sa1 - sa0; if (ma0 > 32) ma0 = 32;
    int mb0 = sb1_ - sb0; if (mb0 > 32) mb0 = 32;
    int idxa = (ma0 > 0) ? csr[sa0 + (c < ma0 ? c : ma0 - 1)] : 0;
    int idxb = (mb0 > 0) ? csr[sb0 + (c < mb0 ? c : mb0 - 1)] : 0;

#pragma unroll
    for (int set = 0; set < 2; ++set) {
        int s0 = set ? sb0 : sa0;
        int s1 = set ? sb1_ : sa1;
        int idx = set ? idxb : idxa;
        float vx = 0.0f, vy = 0.0f;
        for (int base = s0; base < s1; base += 32) {
            int m = s1 - base; if (m > 32) m = 32;
            // prefetch next window's indices
            int nb = base + 32;
            int nm = s1 - nb; if (nm > 32) nm = 32;
            int nidx = (nm > 0) ? csr[nb + (c < nm ? c : nm - 1)] : 0;
            unsigned u[4];
#pragma unroll
            for (int q = 0; q < 4; ++q) {            // 4 unconditional loads
                int e = q * 8 + s;
                int sj = __shfl(idx, e & 31, 32);
                u[q] = xw[(unsigned)sj * 4u + j];
            }
#pragma unroll
            for (int q = 0; q < 4; ++q) {
                unsigned um = (q * 8 + s < m) ? u[q] : 0u;
                vx += lo16f(um); vy += hi16f(um);
            }
            idx = nidx;
        }
        vx += __shfl_down(vx, 16, 32);  vy += __shfl_down(vy, 16, 32);
        vx += __shfl_down(vx, 8, 32);   vy += __shfl_down(vy, 8, 32);
        vx += __shfl_down(vx, 4, 32);   vy += __shfl_down(vy, 4, 32);
        if (c < 4) { sag[g][set][2 * j] = vx; sag[g][set][2 * j + 1] = vy; }
        // same-wave producer/consumer
    }

    int degi = sb1_ - sb0;
    float invc = 1.0f / fmaxf((float)degi, 1.0f);

    float acc = sb1[c];
#pragma unroll
    for (int k = 0; k < ICH; ++k) {
        float xv = ldf(x, (long)node * ICH + k, f32);
        acc += xv * sWs[k * OCH + c]
             + sag[g][0][k] * sWt[k * OCH + c]
             + (sag[g][1][k] * invc) * sWi[k * OCH + c];
    }
    h1b[(long)node * OCH + c] = __float2bfloat16(fmaxf(acc, 0.0f));
    if (c == 0) invc_out[node] = invc;
}

// ---------------------------------------------------------------------------
// Fused block-2 + decoder. 512 thr = 16 nodes. r8 gather structure (8 loads
// in flight) + front-loaded csr indices. Tail: k-major weights -> conflict-
// free ds_read_b32 (lane c hits bank c), sv[g][k] reads are broadcasts.
__global__ __launch_bounds__(512, 8) void final_r10(
        const unsigned* __restrict__ h1u,     // h1 as bf16x2 words, 16/row
        const int* __restrict__ csr, const int* __restrict__ off,
        const float* __restrict__ invc,
        const void* Ws2, const void* b2v, const void* Wt2, const void* Wi2,
        const void* Wd1, const void* bd1, const void* Wd2, const void* bd2,
        void* __restrict__ out, const int* __restrict__ flag) {
    __shared__ float sWcat[96][32];     // k-major: [k][c], conflict-free
    __shared__ float sWd[32][32];       // k-major
    __shared__ float sb2[OCH], sbd1[OCH], swd2[OCH];
    __shared__ float sv[GN][100];       // [h1(32) | sumtp(32) | sumint(32) | pad]
    int t = threadIdx.x;
    int f32 = *flag;
    for (int i = t; i < 96 * 32; i += 512) {
        int k = i >> 5, c = i & 31;
        float w;
        if (k < 32)      w = ldf(Ws2, k * 32 + c, f32) + ((k == c) ? 1.0f : 0.0f);
        else if (k < 64) w = ldf(Wt2, (k - 32) * 32 + c, f32);
        else             w = ldf(Wi2, (k - 64) * 32 + c, f32);
        sWcat[k][c] = w;                 // linear in i
    }
    for (int i = t; i < 32 * 32; i += 512) {
        int k = i >> 5, c = i & 31;
        sWd[k][c] = ldf(Wd1, k * 32 + c, f32);
    }
    if (t < OCH) {
        sb2[t] = ldf(b2v, t, f32); sbd1[t] = ldf(bd1, t, f32); swd2[t] = ldf(Wd2, t, f32);
    }
    __syncthreads();

    int g = t >> 5, c = t & 31;
    int half = c >> 4, l = c & 15;
    int node = blockIdx.x * GN + g;

    // front-load: self row, invc, both sets' extents + first-window indices
    unsigned uself = h1u[(unsigned)node * 16u + l];
    float ic = invc[node];
    int sa0 = off[node],      sa1 = off[node + 1];
    int sb0 = off[NN + node], sb1_ = off[NN + node + 1];
    int ma0 = sa1 - sa0; if (ma0 > 32) ma0 = 32;
    int mb0 = sb1_ - sb0; if (mb0 > 32) mb0 = 32;
    int idxa = (ma0 > 0) ? csr[sa0 + (c < ma0 ? c : ma0 - 1)] : 0;
    int idxb = (mb0 > 0) ? csr[sb0 + (c < mb0 ? c : mb0 - 1)] : 0;

    if (half == 0)
        *(float2*)&sv[g][2 * l] = make_float2(lo16f(uself), hi16f(uself));

#pragma unroll
    for (int set = 0; set < 2; ++set) {
        int s0 = set ? sb0 : sa0;
        int s1 = set ? sb1_ : sa1;
        int idx = set ? idxb : idxa;
        float vx = 0.0f, vy = 0.0f;
        for (int base = s0; base < s1; base += 32) {
            int m = s1 - base; if (m > 32) m = 32;
            int nb = base + 32;
            int nm = s1 - nb; if (nm > 32) nm = 32;
            int nidx = (nm > 0) ? csr[nb + (c < nm ? c : nm - 1)] : 0;
            for (int b = 0; b < m; b += 16) {
                unsigned uu[8];
#pragma unroll
                for (int q = 0; q < 8; ++q) {        // 8 unconditional loads
                    int e = b + 2 * q + half;
                    int sj = __shfl(idx, e & 31, 32);
                    uu[q] = h1u[(unsigned)sj * 16u + l];
                }
#pragma unroll
                for (int q = 0; q < 8; ++q) {
                    unsigned um = (b + 2 * q + half < m) ? uu[q] : 0u;
                    vx += lo16f(um); vy += hi16f(um);
                }
            }
            idx = nidx;
        }
        vx += __shfl_down(vx, 16, 32);
        vy += __shfl_down(vy, 16, 32);
        if (half == 0) {
            float sc = (set == 1) ? ic : 1.0f;
            *(float2*)&sv[g][32 + set * 32 + 2 * l] = make_float2(vx * sc, vy * sc);
        }
    }
    // same-wave LDS producer/consumer: program order suffices

    float acc = sb2[c];
#pragma unroll 4
    for (int k = 0; k < 96; ++k)
        acc += sv[g][k] * sWcat[k][c];   // broadcast * conflict-free
    float h2 = fmaxf(acc, 0.0f);
    sv[g][c] = h2;            // same-wave lockstep => safe overwrite

    float acc2 = sbd1[c];
#pragma unroll 4
    for (int k = 0; k < 32; ++k)
        acc2 += sv[g][k] * sWd[k][c];
    float h3 = fmaxf(acc2, 0.0f);

    float p = h3 * swd2[c];
#pragma unroll
    for (int offs = 16; offs; offs >>= 1) p += __shfl_down(p, offs, 32);
    if (c == 0) {
        float z = p + ldf(bd2, 0, f32);
        float sgm = 1.0f / (1.0f + expf(-z));
        if (f32) ((float*)out)[node] = sgm;
        else     ((__hip_bfloat16*)out)[node] = __float2bfloat16(sgm);
    }
}

// ---------------------------------------------------------------------------
extern "C" void kernel_launch(void* const* d_in, const int* in_sizes, int n_in,
                              void* d_out, int out_size, void* d_ws, size_t ws_size,
                              hipStream_t stream) {
    const void* x      = d_in[0];
    const int* edge_tp = (const int*)d_in[1];
    const int* edge_int= (const int*)d_in[2];
    const void* Ws1 = d_in[3], *b1 = d_in[4], *Wt1 = d_in[5], *Wi1 = d_in[6], *Wr1 = d_in[7];
    const void* Ws2 = d_in[8], *b2 = d_in[9];
    const void* Wt2 = d_in[10], *Wi2 = d_in[11];
    const void* Wd1 = d_in[12], *bd1 = d_in[13], *Wd2 = d_in[14], *bd2 = d_in[15];

    const int E_tp  = in_sizes[1] / 2;
    const int E_int = in_sizes[2] / 2;
    const int E     = E_tp + E_int;

    // Workspace (4B units), ~29 MB (same proven-safe layout as r8):
    // [flag:64][mat: NBK*PBLK][bsum:256][off: 2N+2][xw: 4N][csr: E][union: E]
    //   union holds part during CSR build, then h1b(16N)+invc(N).
    int*      flag = (int*)d_ws;
    int*      mat  = flag + 64;
    int*      bsum = mat + NBK * PBLK;
    int*      off  = bsum + 256;
    unsigned* xw   = (unsigned*)(off + 2 * NN + 2);
    int*      csr  = (int*)(xw + (size_t)4 * NN);
    int*      un   = csr + E;
    unsigned* part = (unsigned*)un;
    __hip_bfloat16* h1b = (__hip_bfloat16*)un;
    unsigned* h1u  = (unsigned*)un;
    float*    invc = (float*)(un + (size_t)16 * NN);

    const int* src_tp  = edge_tp;
    const int* dst_tp  = edge_tp + E_tp;
    const int* src_int = edge_int;
    const int* dst_int = edge_int + E_int;

    // ---- CSR build (detect fused into partA1, xpack into passB) ----
    const int nmat = NBK * PBLK;
    const int nb = (nmat + 1023) / 1024;
    partA1_r10<<<PBLK, 1024, 0, stream>>>(dst_tp, dst_int, mat, E_tp, E, x, flag);
    scan_block_r10<<<nb, 256, 0, stream>>>(mat, mat, bsum, nmat);
    scan_add_r10<<<(nmat + 255) / 256, 256, 0, stream>>>(mat, bsum, nmat, nb);
    partA2_r10<<<PBLK, 1024, 0, stream>>>(src_tp, dst_tp, src_int, dst_int,
                                          mat, part, E_tp, E);
    passB_r10<<<NBK, 256, 0, stream>>>(part, mat, off, csr, E, x, xw, flag);

    // ---- block 1: dword gather, front-loaded indices ----
    node1_r10<<<NN / 8, 256, 0, stream>>>(x, xw, csr, off, Ws1, b1, Wt1, Wi1, Wr1,
                                          h1b, invc, flag);

    // ---- block 2 + decoder: 8-deep gather, conflict-free k-major tail ----
    final_r10<<<NN / GN, 512, 0, stream>>>(h1u, csr, off, invc,
                                           Ws2, b2, Wt2, Wi2,
                                           Wd1, bd1, Wd2, bd2, d_out, flag);
}